// Round 3
// baseline (1795.233 us; speedup 1.0000x reference)
//
#include <hip/hip_runtime.h>

#define BATCH 32
#define NV    10242
#define NF    20480
#define NBB   64          // 2 hemis * 32 batches ; lane = bb
#define NSTEPS 10
#define STEPSZ 0.1f
#define EPSV   1e-8f

#define VPW    4                          // vertices per wave
#define GROUPS ((NV + 15) / 16)           // 641 blocks' worth of 16-vertex groups
#define GPC    ((GROUPS + 7) / 8)         // 81 groups per XCD chunk
#define NBLK   (GPC * 8)                  // 648 blocks

// ---------------- workspace layout: all state transposed to [V][ch][NBB] ----------------
static constexpr size_t OFF_V    = 0;                               // [V][3][NBB]
static constexpr size_t OFF_SULC = OFF_V    + (size_t)NV * 3 * NBB; // [V][NBB]
static constexpr size_t OFF_FEAT = OFF_SULC + (size_t)NV * NBB;     // [V][9][NBB]
static constexpr size_t OFF_H    = OFF_FEAT + (size_t)NV * 9 * NBB; // [V][16][NBB]
static constexpr size_t OFF_CSZ  = OFF_H    + (size_t)NV * 16 * NBB;// [6][NBB]
static constexpr size_t OFF_INT  = OFF_CSZ  + 6 * NBB;
// int region: deg[NV], nbrB[NV*6], nbrC[NV*6]

__device__ __forceinline__ int rfl(int x) { return __builtin_amdgcn_readfirstlane(x); }
// XCD swizzle: chunk = blockIdx%8 owns contiguous GPC groups -> contiguous vertex range per XCD L2
__device__ __forceinline__ int swiz(int b) { return (b & 7) * GPC + (b >> 3); }

// ---------------- adjacency build ----------------
__global__ __launch_bounds__(256) void k_zero_deg(int* deg) {
    int i = blockIdx.x * 256 + threadIdx.x;
    if (i < NV) deg[i] = 0;
}

__global__ __launch_bounds__(256) void k_build(const int* __restrict__ faces,
                                               int* deg, int* nbrB, int* nbrC) {
    int fi = blockIdx.x * 256 + threadIdx.x;
    if (fi >= NF) return;
    int vv[3] = {faces[fi * 3 + 0], faces[fi * 3 + 1], faces[fi * 3 + 2]};
#pragma unroll
    for (int c = 0; c < 3; c++) {
        int vtx = vv[c];
        int s = atomicAdd(&deg[vtx], 1);
        nbrB[vtx * 6 + s] = vv[(c + 1) % 3];   // next corner = dedup'd neighbor
        nbrC[vtx * 6 + s] = vv[(c + 2) % 3];   // prev corner
    }
}

// ---------------- bbox + normalize + transpose-in (one block per bb) ----------------
__global__ __launch_bounds__(256) void k_norm(const float* __restrict__ lh,
                                              const float* __restrict__ rh,
                                              float* __restrict__ v,
                                              float* __restrict__ sulc,
                                              float* __restrict__ csz) {
    int bb = blockIdx.x;
    const float* src = (bb < BATCH) ? (lh + (size_t)bb * NV * 3)
                                    : (rh + (size_t)(bb - BATCH) * NV * 3);
    __shared__ float smin[3][256], smax[3][256];
    float mn[3] = {1e30f, 1e30f, 1e30f}, mx[3] = {-1e30f, -1e30f, -1e30f};
    for (int i = threadIdx.x; i < NV; i += 256) {
#pragma unroll
        for (int c = 0; c < 3; c++) {
            float x = src[i * 3 + c];
            mn[c] = fminf(mn[c], x);
            mx[c] = fmaxf(mx[c], x);
        }
    }
#pragma unroll
    for (int c = 0; c < 3; c++) { smin[c][threadIdx.x] = mn[c]; smax[c][threadIdx.x] = mx[c]; }
    __syncthreads();
    for (int s = 128; s > 0; s >>= 1) {
        if (threadIdx.x < s) {
#pragma unroll
            for (int c = 0; c < 3; c++) {
                smin[c][threadIdx.x] = fminf(smin[c][threadIdx.x], smin[c][threadIdx.x + s]);
                smax[c][threadIdx.x] = fmaxf(smax[c][threadIdx.x], smax[c][threadIdx.x + s]);
            }
        }
        __syncthreads();
    }
    float ctr[3], sz[3];
#pragma unroll
    for (int c = 0; c < 3; c++) {
        ctr[c] = 0.5f * (smin[c][0] + smax[c][0]);
        sz[c]  = smax[c][0] - ctr[c];
    }
    if (threadIdx.x == 0) {
#pragma unroll
        for (int c = 0; c < 3; c++) { csz[c * NBB + bb] = ctr[c]; csz[(3 + c) * NBB + bb] = sz[c]; }
    }
    for (int i = threadIdx.x; i < NV; i += 256) {
#pragma unroll
        for (int c = 0; c < 3; c++)
            v[((size_t)i * 3 + c) * NBB + bb] = (src[i * 3 + c] - ctr[c]) / sz[c];
        sulc[(size_t)i * NBB + bb] = 0.f;
    }
}

// ---------------- per-step: geometry -> feats[9] = (v, n, 0.5*lap) ----------------
__global__ __launch_bounds__(256) void k_geom(const float* __restrict__ v,
                                              const int* __restrict__ deg,
                                              const int* __restrict__ nbrB,
                                              const int* __restrict__ nbrC,
                                              float* __restrict__ feat) {
    int g = swiz(blockIdx.x);
    if (g >= GROUPS) return;
    int t = threadIdx.x, lane = t & 63;
    int vbase = rfl(g * 16 + (t >> 6) * VPW);
    int nv = NV - vbase; if (nv > VPW) nv = VPW; if (nv <= 0) return;
    float sgn = (lane < BATCH) ? 1.f : -1.f;
#pragma unroll
    for (int q = 0; q < VPW; q++) {
        if (q >= nv) break;
        int vi = vbase + q;
        float ax_ = v[((size_t)vi * 3 + 0) * NBB + lane];
        float ay_ = v[((size_t)vi * 3 + 1) * NBB + lane];
        float az_ = v[((size_t)vi * 3 + 2) * NBB + lane];
        float vnx = 0.f, vny = 0.f, vnz = 0.f, lx = 0.f, ly = 0.f, lz = 0.f;
        int d = rfl(deg[vi]);
        for (int k = 0; k < d; k++) {
            int iB = rfl(nbrB[vi * 6 + k]);
            int iC = rfl(nbrC[vi * 6 + k]);
            float bx = v[((size_t)iB * 3 + 0) * NBB + lane];
            float by = v[((size_t)iB * 3 + 1) * NBB + lane];
            float bz = v[((size_t)iB * 3 + 2) * NBB + lane];
            float cx = v[((size_t)iC * 3 + 0) * NBB + lane];
            float cy = v[((size_t)iC * 3 + 1) * NBB + lane];
            float cz = v[((size_t)iC * 3 + 2) * NBB + lane];
            float e1x = bx - ax_, e1y = by - ay_, e1z = bz - az_;   // B - A
            float e2x = cx - ax_, e2y = cy - ay_, e2z = cz - az_;   // C - A
            float fnx = e1y * e2z - e1z * e2y;                      // face normal
            float fny = e1z * e2x - e1x * e2z;
            float fnz = e1x * e2y - e1y * e2x;
            vnx += fnx; vny += fny; vnz += fnz;
            float denom = sqrtf(fnx * fnx + fny * fny + fnz * fnz) + EPSV; // 2*area+eps
            float ux = cx - bx, uy = cy - by, uz = cz - bz;
            float wx = ax_ - bx, wy = ay_ - by, wz = az_ - bz;
            float cB = (ux * wx + uy * wy + uz * wz) / denom;       // cot at B
            float rx = ax_ - cx, ry = ay_ - cy, rz = az_ - cz;
            float sx = bx - cx, sy = by - cy, sz2 = bz - cz;
            float cC = (rx * sx + ry * sy + rz * sz2) / denom;      // cot at C
            lx += cC * e1x + cB * e2x;
            ly += cC * e1y + cB * e2y;
            lz += cC * e1z + cB * e2z;
        }
        vnx *= sgn; vny *= sgn; vnz *= sgn;
        float nn = sqrtf(vnx * vnx + vny * vny + vnz * vnz) + EPSV;
        float* fp = feat + (size_t)vi * 9 * NBB + lane;
        fp[0 * NBB] = ax_; fp[1 * NBB] = ay_; fp[2 * NBB] = az_;
        fp[3 * NBB] = vnx / nn; fp[4 * NBB] = vny / nn; fp[5 * NBB] = vnz / nn;
        fp[6 * NBB] = 0.5f * lx; fp[7 * NBB] = 0.5f * ly; fp[8 * NBB] = 0.5f * lz;
    }
}

// ---------------- per-step: layer1  h = relu(feats@W1s + mean_nbr(feats)@W1n + b1) ----------------
__global__ __launch_bounds__(256) void k_layer1(const float* __restrict__ feat,
                                                const int* __restrict__ deg,
                                                const int* __restrict__ nbrB,
                                                const float* __restrict__ W1s,
                                                const float* __restrict__ W1n,
                                                const float* __restrict__ b1,
                                                float* __restrict__ h) {
    // transposed: sWs[j*12+i] = W1s[i*16+j] (row padded 9->12, contiguous in i for b128 merges)
    __shared__ float sWs[16 * 12], sWn[16 * 12], sb[16];
    int t = threadIdx.x;
    if (t < 144) {
        int i = t >> 4, j = t & 15;
        sWs[j * 12 + i] = W1s[t];
        sWn[j * 12 + i] = W1n[t];
    }
    if (t < 16) sb[t] = b1[t];
    __syncthreads();
    int g = swiz(blockIdx.x);
    if (g >= GROUPS) return;
    int lane = t & 63;
    int vbase = rfl(g * 16 + (t >> 6) * VPW);
    int nv = NV - vbase; if (nv > VPW) nv = VPW; if (nv <= 0) return;
    float own[VPW][9], m[VPW][9];
#pragma unroll
    for (int q = 0; q < VPW; q++) {
        if (q < nv) {
            int vi = vbase + q;
            const float* fp = feat + (size_t)vi * 9 * NBB + lane;
#pragma unroll
            for (int i = 0; i < 9; i++) { own[q][i] = fp[i * NBB]; m[q][i] = 0.f; }
            int d = rfl(deg[vi]);
            for (int k = 0; k < d; k++) {
                int u = rfl(nbrB[vi * 6 + k]);
                const float* fu = feat + (size_t)u * 9 * NBB + lane;
#pragma unroll
                for (int i = 0; i < 9; i++) m[q][i] += fu[i * NBB];
            }
            float inv = 1.f / (float)d;
#pragma unroll
            for (int i = 0; i < 9; i++) m[q][i] *= inv;
        } else {
#pragma unroll
            for (int i = 0; i < 9; i++) { own[q][i] = 0.f; m[q][i] = 0.f; }
        }
    }
#pragma unroll 4
    for (int j = 0; j < 16; j++) {
        float acc[VPW];
#pragma unroll
        for (int q = 0; q < VPW; q++) acc[q] = sb[j];
#pragma unroll
        for (int i = 0; i < 9; i++) {
            float ws = sWs[j * 12 + i], wn = sWn[j * 12 + i];
#pragma unroll
            for (int q = 0; q < VPW; q++) acc[q] += own[q][i] * ws + m[q][i] * wn;
        }
#pragma unroll
        for (int q = 0; q < VPW; q++)
            if (q < nv) h[((size_t)(vbase + q) * 16 + j) * NBB + lane] = fmaxf(acc[q], 0.f);
    }
}

// ---------------- per-step: layer2 + output head + state update ----------------
__global__ __launch_bounds__(256, 3) void k_layer2(const float* __restrict__ h,
                                                   const float* __restrict__ feat,
                                                   const int* __restrict__ deg,
                                                   const int* __restrict__ nbrB,
                                                   const float* __restrict__ W2s,
                                                   const float* __restrict__ W2n,
                                                   const float* __restrict__ b2,
                                                   const float* __restrict__ Wo,
                                                   const float* __restrict__ bo,
                                                   float* __restrict__ v,
                                                   float* __restrict__ sulc) {
    // transposed: sWs[j*16+i] = W2s[i*16+j]; sWo[c*16+j] = Wo[j*3+c]
    __shared__ float sWs[256], sWn[256], sb[16], sWo[48], sbo[3];
    int t = threadIdx.x;
    {
        int i = t >> 4, j = t & 15;
        sWs[j * 16 + i] = W2s[t];
        sWn[j * 16 + i] = W2n[t];
    }
    if (t < 48) { int i = t / 3, c = t - 3 * i; sWo[c * 16 + i] = Wo[t]; }
    if (t < 16) sb[t] = b2[t];
    if (t < 3)  sbo[t] = bo[t];
    __syncthreads();
    int g = swiz(blockIdx.x);
    if (g >= GROUPS) return;
    int lane = t & 63;
    int vbase = rfl(g * 16 + (t >> 6) * VPW);
    int nv = NV - vbase; if (nv > VPW) nv = VPW; if (nv <= 0) return;
    float own[VPW][16], m[VPW][16];
#pragma unroll
    for (int q = 0; q < VPW; q++) {
        if (q < nv) {
            int vi = vbase + q;
            const float* hp = h + (size_t)vi * 16 * NBB + lane;
#pragma unroll
            for (int i = 0; i < 16; i++) { own[q][i] = hp[i * NBB]; m[q][i] = 0.f; }
            int d = rfl(deg[vi]);
            for (int k = 0; k < d; k++) {
                int u = rfl(nbrB[vi * 6 + k]);
                const float* hu = h + (size_t)u * 16 * NBB + lane;
#pragma unroll
                for (int i = 0; i < 16; i++) m[q][i] += hu[i * NBB];
            }
            float inv = 1.f / (float)d;
#pragma unroll
            for (int i = 0; i < 16; i++) m[q][i] *= inv;
        } else {
#pragma unroll
            for (int i = 0; i < 16; i++) { own[q][i] = 0.f; m[q][i] = 0.f; }
        }
    }
    float dv[VPW][3];
#pragma unroll
    for (int q = 0; q < VPW; q++)
#pragma unroll
        for (int c = 0; c < 3; c++) dv[q][c] = sbo[c];
#pragma unroll 4
    for (int j = 0; j < 16; j++) {
        float acc[VPW];
#pragma unroll
        for (int q = 0; q < VPW; q++) acc[q] = sb[j];
#pragma unroll
        for (int i = 0; i < 16; i++) {
            float ws = sWs[j * 16 + i], wn = sWn[j * 16 + i];
#pragma unroll
            for (int q = 0; q < VPW; q++) acc[q] += own[q][i] * ws + m[q][i] * wn;
        }
        float wo0 = sWo[0 * 16 + j], wo1 = sWo[1 * 16 + j], wo2 = sWo[2 * 16 + j];
#pragma unroll
        for (int q = 0; q < VPW; q++) {
            float h2 = fmaxf(acc[q], 0.f);     // fused head: h2 never materialized
            dv[q][0] += h2 * wo0;
            dv[q][1] += h2 * wo1;
            dv[q][2] += h2 * wo2;
        }
    }
#pragma unroll
    for (int q = 0; q < VPW; q++) {
        if (q >= nv) break;
        int vi = vbase + q;
        float* vp = v + (size_t)vi * 3 * NBB + lane;
        const float* np_ = feat + ((size_t)vi * 9 + 3) * NBB + lane;  // this step's normals
        vp[0 * NBB] += STEPSZ * dv[q][0];
        vp[1 * NBB] += STEPSZ * dv[q][1];
        vp[2 * NBB] += STEPSZ * dv[q][2];
        sulc[(size_t)vi * NBB + lane] +=
            STEPSZ * (np_[0 * NBB] * dv[q][0] + np_[1 * NBB] * dv[q][1] + np_[2 * NBB] * dv[q][2]);
    }
}

// ---------------- output: (2,B,V,4) = (v*size, sulc) — transpose-out ----------------
__global__ __launch_bounds__(256) void k_out(const float* __restrict__ v,
                                             const float* __restrict__ sulc,
                                             const float* __restrict__ csz,
                                             float4* __restrict__ out) {
    int vi = blockIdx.x * 256 + threadIdx.x;
    int bb = blockIdx.y;
    if (vi >= NV) return;
    float4 o;
    o.x = v[((size_t)vi * 3 + 0) * NBB + bb] * csz[(3 + 0) * NBB + bb];
    o.y = v[((size_t)vi * 3 + 1) * NBB + bb] * csz[(3 + 1) * NBB + bb];
    o.z = v[((size_t)vi * 3 + 2) * NBB + bb] * csz[(3 + 2) * NBB + bb];
    o.w = sulc[(size_t)vi * NBB + bb];
    out[(size_t)bb * NV + vi] = o;
}

extern "C" void kernel_launch(void* const* d_in, const int* in_sizes, int n_in,
                              void* d_out, int out_size, void* d_ws, size_t ws_size,
                              hipStream_t stream) {
    const float* lh  = (const float*)d_in[0];
    const float* rh  = (const float*)d_in[1];
    const float* W1s = (const float*)d_in[2];
    const float* W1n = (const float*)d_in[3];
    const float* b1  = (const float*)d_in[4];
    const float* W2s = (const float*)d_in[5];
    const float* W2n = (const float*)d_in[6];
    const float* b2  = (const float*)d_in[7];
    const float* Wo  = (const float*)d_in[8];
    const float* bo  = (const float*)d_in[9];
    const int* faces = (const int*)d_in[10];

    float* ws   = (float*)d_ws;
    float* v    = ws + OFF_V;
    float* sulc = ws + OFF_SULC;
    float* feat = ws + OFF_FEAT;
    float* h    = ws + OFF_H;
    float* csz  = ws + OFF_CSZ;
    int* ibase  = (int*)(ws + OFF_INT);
    int* deg    = ibase;
    int* nbrB   = ibase + NV;
    int* nbrC   = ibase + NV + NV * 6;

    dim3 gv(NBLK);   // 648 blocks, 16 verts/block, XCD-swizzled

    k_zero_deg<<<(NV + 255) / 256, 256, 0, stream>>>(deg);
    k_build<<<(NF + 255) / 256, 256, 0, stream>>>(faces, deg, nbrB, nbrC);
    k_norm<<<NBB, 256, 0, stream>>>(lh, rh, v, sulc, csz);

    for (int s = 0; s < NSTEPS; s++) {
        k_geom<<<gv, 256, 0, stream>>>(v, deg, nbrB, nbrC, feat);
        k_layer1<<<gv, 256, 0, stream>>>(feat, deg, nbrB, W1s, W1n, b1, h);
        k_layer2<<<gv, 256, 0, stream>>>(h, feat, deg, nbrB, W2s, W2n, b2, Wo, bo, v, sulc);
    }
    k_out<<<dim3((NV + 255) / 256, NBB), 256, 0, stream>>>(v, sulc, csz, (float4*)d_out);
}